// Round 14
// baseline (385.175 us; speedup 1.0000x reference)
//
#include <hip/hip_runtime.h>
#include <hip/hip_bf16.h>

// Problem constants (from reference)
#define N_NODES 50000
#define N_REL   8
#define DIM     128      // IN_DIM == HID == 128
#define N_EDGES 800000
#define N_TRIP  100000
#define NSEG    (N_NODES * N_REL)   // 400000
#define NBUCKET 196                 // ceil(50000/256) dst buckets
#define CAP     6144                // slack slots per bucket (mean 4082)

typedef __attribute__((ext_vector_type(8))) short bf16x8;
typedef __attribute__((ext_vector_type(4))) float f32x4;

static __device__ __forceinline__ unsigned short f2b(float f) {
    __hip_bfloat16 h = __float2bfloat16(f);
    return *reinterpret_cast<unsigned short*>(&h);
}
static __device__ __forceinline__ float blo(unsigned int u) {
    return __uint_as_float(u << 16);
}
static __device__ __forceinline__ float bhi(unsigned int u) {
    return __uint_as_float(u & 0xffff0000u);
}
// XOR-swizzled LDS offset (units: shorts): chunk c of row n -> slot (c ^ (n&7))
static __device__ __forceinline__ int lds_off(int row, int chunk) {
    return (row * 16 + (chunk ^ (row & 7))) * 8;
}

// ---------------------------------------------------------------------------
// bucket_scatter: bin edges by dst>>8 into fixed-capacity slack regions.
// packed word: src[0:16) | rel[16:19) | dstLow[19:27)
__global__ __launch_bounds__(256) void bucket_scatter(
        const int* __restrict__ edge_index,
        const int* __restrict__ edge_type,
        int* __restrict__ gcnt,
        unsigned int* __restrict__ slack) {
    __shared__ int hist[NBUCKET];
    __shared__ int cur[NBUCKET];
    int tid = threadIdx.x;
    for (int i = tid; i < NBUCKET; i += 256) hist[i] = 0;
    __syncthreads();
    int base = blockIdx.x * 4096;
    unsigned int w[16];
    int bk[16];
    #pragma unroll
    for (int i = 0; i < 16; ++i) {
        int e = base + i * 256 + tid;
        if (e < N_EDGES) {
            int src = edge_index[e];
            int dst = edge_index[N_EDGES + e];
            int r = edge_type[e];
            w[i] = (unsigned int)src | ((unsigned int)r << 16) |
                   ((unsigned int)(dst & 255) << 19);
            bk[i] = dst >> 8;
            atomicAdd(&hist[bk[i]], 1);
        } else {
            bk[i] = -1;
        }
    }
    __syncthreads();
    for (int i = tid; i < NBUCKET; i += 256)
        cur[i] = atomicAdd(&gcnt[i], hist[i]);
    __syncthreads();
    #pragma unroll
    for (int i = 0; i < 16; ++i) {
        if (bk[i] >= 0) {
            int p = atomicAdd(&cur[bk[i]], 1);
            if (p < CAP) slack[(size_t)bk[i] * CAP + p] = w[i];
        }
    }
}

// ---------------------------------------------------------------------------
// bucket_scan: exclusive scan of 196 bucket counts; also set sentinel.
__global__ void bucket_scan(const int* __restrict__ gcnt,
                            int* __restrict__ gbase,
                            int* __restrict__ offsets) {
    __shared__ int sh[256];
    int t = threadIdx.x;
    int v = (t < NBUCKET) ? gcnt[t] : 0;
    sh[t] = v;
    __syncthreads();
    #pragma unroll
    for (int off = 1; off < 256; off <<= 1) {
        int x = (t >= off) ? sh[t - off] : 0;
        __syncthreads();
        sh[t] += x;
        __syncthreads();
    }
    if (t < NBUCKET) gbase[t] = sh[t] - v;
    if (t == 0) offsets[NSEG] = N_EDGES;
}

// ---------------------------------------------------------------------------
// bucket_sort: one block per bucket. LDS counting sort over 2048 local segs
// (dstLow*8+rel). Writes sorted_pack (src|rel<<16), offsets, and invcnt.
__global__ __launch_bounds__(256) void bucket_sort(
        const unsigned int* __restrict__ slack,
        const int* __restrict__ gcnt,
        const int* __restrict__ gbase,
        unsigned int* __restrict__ sorted_pack,
        int* __restrict__ offsets,
        float* __restrict__ invcnt) {
    __shared__ unsigned int ebuf[CAP];   // 24 KB
    __shared__ unsigned int obuf[CAP];   // 24 KB
    __shared__ int hist[2048];           // 8 KB (later reused as cursor)
    __shared__ int excl[2048];           // 8 KB
    __shared__ int sh[256];
    int b = blockIdx.x, t = threadIdx.x;
    int n = gcnt[b]; if (n > CAP) n = CAP;
    int bb = gbase[b];
    for (int i = t; i < n; i += 256) ebuf[i] = slack[(size_t)b * CAP + i];
    for (int i = t; i < 2048; i += 256) hist[i] = 0;
    __syncthreads();
    for (int i = t; i < n; i += 256) {
        unsigned int w = ebuf[i];
        int seg = (int)((w >> 19) << 3) | (int)((w >> 16) & 7u);
        atomicAdd(&hist[seg], 1);
    }
    __syncthreads();
    // blocked exclusive scan over 2048: thread t owns [t*8, t*8+8)
    int c[8];
    int s = 0;
    #pragma unroll
    for (int j = 0; j < 8; ++j) { c[j] = hist[t * 8 + j]; s += c[j]; }
    sh[t] = s;
    __syncthreads();
    #pragma unroll
    for (int off = 1; off < 256; off <<= 1) {
        int x = (t >= off) ? sh[t - off] : 0;
        __syncthreads();
        sh[t] += x;
        __syncthreads();
    }
    int ex = sh[t] - s;
    #pragma unroll
    for (int j = 0; j < 8; ++j) { excl[t * 8 + j] = ex; ex += c[j]; }
    __syncthreads();
    #pragma unroll
    for (int j = 0; j < 8; ++j) hist[t * 8 + j] = excl[t * 8 + j];  // cursor
    __syncthreads();
    for (int i = t; i < n; i += 256) {
        unsigned int w = ebuf[i];
        int seg = (int)((w >> 19) << 3) | (int)((w >> 16) & 7u);
        int p = atomicAdd(&hist[seg], 1);
        obuf[p] = w & 0x7ffffu;          // src | rel<<16
    }
    __syncthreads();
    for (int i = t; i < n; i += 256) sorted_pack[bb + i] = obuf[i];
    int segbase = b * 2048;
    #pragma unroll
    for (int j = 0; j < 8; ++j) {
        int gseg = segbase + t * 8 + j;
        if (gseg < NSEG) {
            offsets[gseg] = bb + excl[t * 8 + j];
            invcnt[gseg] = (c[j] > 0) ? 1.0f / (float)c[j] : 0.f;
        }
    }
}

// ---------------------------------------------------------------------------
// cvt_emb: fp32 -> bf16, 2 elems/thread (packed)
__global__ void cvt_emb_kernel(const float* __restrict__ src,
                               unsigned short* __restrict__ dst) {
    int i = blockIdx.x * blockDim.x + threadIdx.x;
    const int npair = N_NODES * DIM / 2;
    if (i >= npair) return;
    float2 v = ((const float2*)src)[i];
    unsigned int p = (unsigned int)f2b(v.x) | ((unsigned int)f2b(v.y) << 16);
    ((unsigned int*)dst)[i] = p;
}

// ---------------------------------------------------------------------------
// cvt_w2: Wt2[s][n][k] bf16 for both layers; s=0 -> root, s>=1 -> W_{s-1}.
__global__ void cvt_w2_kernel(const float* __restrict__ root0,
                              const float* __restrict__ W0,
                              const float* __restrict__ root1,
                              const float* __restrict__ W1,
                              unsigned short* __restrict__ Wt2a,
                              unsigned short* __restrict__ Wt2b) {
    int s = blockIdx.x;        // 0..8
    int n = blockIdx.y;        // 0..127
    int k = threadIdx.x;       // 0..127
    const float* root = blockIdx.z ? root1 : root0;
    const float* W    = blockIdx.z ? W1 : W0;
    unsigned short* Wt2 = blockIdx.z ? Wt2b : Wt2a;
    float v = (s == 0) ? root[k * 128 + n]
                       : W[((size_t)(s - 1) * 128 + k) * 128 + n];
    Wt2[((size_t)s * 128 + n) * 128 + k] = f2b(v);
}

// ---------------------------------------------------------------------------
// gemm_slot: Y[s][n][:] = h[n] @ B_s — ONE SLOT PER BLOCK.
// Grid (782, 2, 9). Each block stages its 16 KB Bs once, hits ONE barrier,
// MFMAs, stores, exits. Store drains happen at block teardown and are
// overlapped by fresh blocks dispatching (no mid-kernel barrier drains).
__global__ __launch_bounds__(256) void gemm_slot(
        const unsigned short* __restrict__ hb,    // N x 128 bf16
        const unsigned short* __restrict__ Wt2,   // 9 x 128(n) x 128(k) bf16
        unsigned short* __restrict__ Y) {         // 9 x N x 128 bf16
    __shared__ unsigned short Bs[64 * 16 * 8];    // 16 KB swizzled

    int tid = threadIdx.x;
    int wave = tid >> 6, lane = tid & 63;
    int wm = wave & 1, wn = wave >> 1;            // 32-row / 32-col half
    int quad = lane >> 4, l16 = lane & 15;
    int row0 = blockIdx.x * 64;
    int col0 = blockIdx.y * 64;
    int s = blockIdx.z;

    // ---- stage B tile (64 n-rows x 128 k), once ----
    {
        int n = tid >> 2, c0 = (tid & 3) * 4;
        const unsigned short* gp = Wt2 + ((size_t)s * 128 + col0 + n) * 128 + c0 * 8;
        #pragma unroll
        for (int q = 0; q < 4; ++q)
            *(bf16x8*)&Bs[lds_off(n, c0 + q)] = *(const bf16x8*)(gp + q * 8);
    }

    // ---- A fragments: direct global -> registers ----
    bf16x8 afr[2][4];
    #pragma unroll
    for (int i = 0; i < 2; ++i) {
        int grow = row0 + wm * 32 + i * 16 + l16;
        if (grow >= N_NODES) grow = N_NODES - 1;
        #pragma unroll
        for (int kk = 0; kk < 4; ++kk)
            afr[i][kk] = *(const bf16x8*)(hb + (size_t)grow * DIM + kk * 32 + quad * 8);
    }
    __syncthreads();   // the only barrier in the kernel

    f32x4 acc[2][2];
    #pragma unroll
    for (int i = 0; i < 2; ++i)
        #pragma unroll
        for (int j = 0; j < 2; ++j) acc[i][j] = (f32x4){0.f, 0.f, 0.f, 0.f};

    #pragma unroll
    for (int kk = 0; kk < 4; ++kk) {
        int chunk = kk * 4 + quad;
        bf16x8 bfr[2];
        #pragma unroll
        for (int j = 0; j < 2; ++j)
            bfr[j] = *(const bf16x8*)&Bs[lds_off(wn * 32 + j * 16 + l16, chunk)];
        #pragma unroll
        for (int i = 0; i < 2; ++i)
            #pragma unroll
            for (int j = 0; j < 2; ++j)
                acc[i][j] = __builtin_amdgcn_mfma_f32_16x16x32_bf16(
                    afr[i][kk], bfr[j], acc[i][j], 0, 0, 0);
    }

    // epilogue: C/D layout col=lane&15, row=(lane>>4)*4+reg
    unsigned short* Ys = Y + (size_t)s * N_NODES * 128;
    #pragma unroll
    for (int i = 0; i < 2; ++i) {
        int gr0 = row0 + wm * 32 + i * 16 + quad * 4;
        #pragma unroll
        for (int j = 0; j < 2; ++j) {
            int gc = col0 + wn * 32 + j * 16 + l16;
            #pragma unroll
            for (int r = 0; r < 4; ++r) {
                int grow = gr0 + r;
                if (grow < N_NODES)
                    Ys[(size_t)grow * 128 + gc] = f2b(acc[i][j][r]);
            }
        }
    }
}

// ---------------------------------------------------------------------------
// aggregate_out: one wave per dst.
// hout[dst,:] = relu(bias + Y[0][dst,:] + sum_e inv[dst,rel_e]*Y[1+rel_e][src_e,:])
__global__ __launch_bounds__(256) void aggregate_out(
        const unsigned short* __restrict__ Y,        // 9 x N x 128 bf16
        const float* __restrict__ bias,              // 128
        const int* __restrict__ offsets,             // NSEG+1 (dst-major)
        const unsigned int* __restrict__ sorted_pack,// N_EDGES: src | rel<<16
        const float* __restrict__ invcnt,            // NSEG
        unsigned short* __restrict__ hout) {         // N x 128 bf16
    int dst = blockIdx.x * 4 + (threadIdx.x >> 6);
    if (dst >= N_NODES) return;
    int lane = threadIdx.x & 63;
    const unsigned int* Yu = (const unsigned int*)Y;

    // root slot (s = 0)
    unsigned int r0 = Yu[(size_t)dst * 64 + lane];
    float a0 = blo(r0), a1 = bhi(r0);

    int beg = offsets[dst * N_REL];
    int end = offsets[dst * N_REL + N_REL];
    for (int base = beg; base < end; base += 64) {
        int np = end - base; if (np > 64) np = 64;
        unsigned int pk = 0; float ivl = 0.f;
        if (lane < np) {
            pk = sorted_pack[base + lane];
            ivl = invcnt[dst * N_REL + (int)(pk >> 16)];
        }
        int j = 0;
        for (; j + 7 < np; j += 8) {
            unsigned int pp[8]; float ii[8];
            #pragma unroll
            for (int q = 0; q < 8; ++q) {
                pp[q] = __shfl((int)pk, j + q, 64);
                ii[q] = __shfl(ivl, j + q, 64);
            }
            unsigned int vv[8];
            #pragma unroll
            for (int q = 0; q < 8; ++q)
                vv[q] = Yu[((size_t)(1 + (pp[q] >> 16)) * N_NODES + (pp[q] & 0xffffu)) * 64 + lane];
            #pragma unroll
            for (int q = 0; q < 8; ++q) {
                a0 = fmaf(blo(vv[q]), ii[q], a0);
                a1 = fmaf(bhi(vv[q]), ii[q], a1);
            }
        }
        for (; j < np; ++j) {
            unsigned int pj = __shfl((int)pk, j, 64);
            float ij = __shfl(ivl, j, 64);
            unsigned int v = Yu[((size_t)(1 + (pj >> 16)) * N_NODES + (pj & 0xffffu)) * 64 + lane];
            a0 = fmaf(blo(v), ij, a0); a1 = fmaf(bhi(v), ij, a1);
        }
    }
    float2 bv = ((const float2*)bias)[lane];
    a0 = fmaxf(a0 + bv.x, 0.f);
    a1 = fmaxf(a1 + bv.y, 0.f);
    unsigned int po = (unsigned int)f2b(a0) | ((unsigned int)f2b(a1) << 16);
    ((unsigned int*)(hout + (size_t)dst * DIM))[lane] = po;
}

// ---------------------------------------------------------------------------
// score: out[t] = sum_d h[head,d]*rel_emb[rel,d]*h[tail,d]  (h in bf16)
__global__ void score_kernel(const unsigned short* __restrict__ hb,
                             const float* __restrict__ rel_emb,
                             const int* __restrict__ head,
                             const int* __restrict__ rel,
                             const int* __restrict__ tail,
                             float* __restrict__ out) {
    int t = blockIdx.x * 4 + (threadIdx.x >> 6);
    if (t >= N_TRIP) return;
    int lane = threadIdx.x & 63;
    unsigned int ph = ((const unsigned int*)(hb + (size_t)head[t] * DIM))[lane];
    unsigned int pt = ((const unsigned int*)(hb + (size_t)tail[t] * DIM))[lane];
    float2 rr = ((const float2*)(rel_emb + (size_t)rel[t] * DIM))[lane];
    float s = blo(ph) * rr.x * blo(pt) + bhi(ph) * rr.y * bhi(pt);
    #pragma unroll
    for (int off = 32; off; off >>= 1) s += __shfl_xor(s, off, 64);
    if (lane == 0) out[t] = s;
}

// ---------------------------------------------------------------------------
extern "C" void kernel_launch(void* const* d_in, const int* in_sizes, int n_in,
                              void* d_out, int out_size, void* d_ws, size_t ws_size,
                              hipStream_t stream) {
    const float* emb     = (const float*)d_in[0];
    const float* W0      = (const float*)d_in[1];
    const float* root0   = (const float*)d_in[2];
    const float* b0      = (const float*)d_in[3];
    const float* W1      = (const float*)d_in[4];
    const float* root1   = (const float*)d_in[5];
    const float* b1      = (const float*)d_in[6];
    const float* rel_emb = (const float*)d_in[7];
    const int* edge_index = (const int*)d_in[8];
    const int* edge_type  = (const int*)d_in[9];
    const int* head_idx   = (const int*)d_in[10];
    const int* rel_idx    = (const int*)d_in[11];
    const int* tail_idx   = (const int*)d_in[12];
    float* out = (float*)d_out;

    // workspace layout (~166 MB, all disjoint):
    char* p = (char*)d_ws;
    size_t y_bytes   = (size_t)9 * N_NODES * DIM * sizeof(unsigned short); // 115.2 MB
    size_t hb_bytes  = (size_t)N_NODES * DIM * sizeof(unsigned short);     // 12.8 MB
    size_t wt2_bytes = (size_t)9 * 128 * 128 * sizeof(unsigned short);     // 294912 B
    unsigned short* Y    = (unsigned short*)p; p += y_bytes;
    unsigned short* embb = (unsigned short*)p; p += hb_bytes;
    unsigned short* h1b  = (unsigned short*)p; p += hb_bytes;
    unsigned short* h2b  = (unsigned short*)p; p += hb_bytes;
    unsigned short* Wt2a = (unsigned short*)p; p += wt2_bytes;
    unsigned short* Wt2b = (unsigned short*)p; p += wt2_bytes;
    int* offsets = (int*)p;           p += (size_t)(NSEG + 1) * sizeof(int);
    float* invcnt = (float*)p;        p += (size_t)NSEG * sizeof(float);
    unsigned int* sorted_pack = (unsigned int*)p; p += (size_t)N_EDGES * sizeof(unsigned int);
    unsigned int* slack = (unsigned int*)p; p += (size_t)NBUCKET * CAP * sizeof(unsigned int);
    int* gcnt  = (int*)p;             p += (size_t)NBUCKET * sizeof(int);
    int* gbase = (int*)p;
    (void)ws_size; (void)in_sizes; (void)n_in; (void)out_size;

    dim3 blk256(256);

    // ---- 2-pass bucket sort of edges by (dst, rel), dst-major ----
    hipMemsetAsync(gcnt, 0, (size_t)NBUCKET * sizeof(int), stream);
    bucket_scatter<<<(N_EDGES + 4095) / 4096, blk256, 0, stream>>>(edge_index, edge_type,
                                                                   gcnt, slack);
    bucket_scan<<<1, 256, 0, stream>>>(gcnt, gbase, offsets);
    bucket_sort<<<NBUCKET, blk256, 0, stream>>>(slack, gcnt, gbase, sorted_pack,
                                                offsets, invcnt);

    // ---- precision conversions ----
    cvt_emb_kernel<<<(N_NODES * DIM / 2 + 255) / 256, blk256, 0, stream>>>(emb, embb);
    cvt_w2_kernel<<<dim3(9, 128, 2), 128, 0, stream>>>(root0, W0, root1, W1, Wt2a, Wt2b);

    dim3 ggrid((N_NODES + 63) / 64, 2, 9);         // 782 x 2 x 9 = 14076 blocks
    int agrid = (N_NODES + 3) / 4;                 // 12500

    // ---- layer 0: transform then aggregate ----
    gemm_slot<<<ggrid, blk256, 0, stream>>>(embb, Wt2a, Y);
    aggregate_out<<<agrid, blk256, 0, stream>>>(Y, b0, offsets, sorted_pack, invcnt, h1b);

    // ---- layer 1 ----
    gemm_slot<<<ggrid, blk256, 0, stream>>>(h1b, Wt2b, Y);
    aggregate_out<<<agrid, blk256, 0, stream>>>(Y, b1, offsets, sorted_pack, invcnt, h2b);

    // ---- score ----
    score_kernel<<<(N_TRIP + 3) / 4, blk256, 0, stream>>>(h2b, rel_emb, head_idx, rel_idx,
                                                          tail_idx, out);
}

// Round 15
// 307.891 us; speedup vs baseline: 1.2510x; 1.2510x over previous
//
#include <hip/hip_runtime.h>
#include <hip/hip_bf16.h>

// Problem constants (from reference)
#define N_NODES 50000
#define N_REL   8
#define DIM     128      // IN_DIM == HID == 128
#define N_EDGES 800000
#define N_TRIP  100000
#define NSEG    (N_NODES * N_REL)   // 400000
#define NBUCKET 196                 // ceil(50000/256) dst buckets
#define CAP     6144                // slack slots per bucket (mean 4082)

typedef __attribute__((ext_vector_type(8))) short bf16x8;
typedef __attribute__((ext_vector_type(4))) float f32x4;

static __device__ __forceinline__ unsigned short f2b(float f) {
    __hip_bfloat16 h = __float2bfloat16(f);
    return *reinterpret_cast<unsigned short*>(&h);
}
static __device__ __forceinline__ float blo(unsigned int u) {
    return __uint_as_float(u << 16);
}
static __device__ __forceinline__ float bhi(unsigned int u) {
    return __uint_as_float(u & 0xffff0000u);
}
// XOR-swizzled LDS offset (units: shorts): chunk c of row n -> slot (c ^ (n&7))
static __device__ __forceinline__ int lds_off(int row, int chunk) {
    return (row * 16 + (chunk ^ (row & 7))) * 8;
}

// ---------------------------------------------------------------------------
// bucket_scatter: bin edges by dst>>8 into fixed-capacity slack regions.
// packed word: src[0:16) | rel[16:19) | dstLow[19:27)
__global__ __launch_bounds__(256) void bucket_scatter(
        const int* __restrict__ edge_index,
        const int* __restrict__ edge_type,
        int* __restrict__ gcnt,
        unsigned int* __restrict__ slack) {
    __shared__ int hist[NBUCKET];
    __shared__ int cur[NBUCKET];
    int tid = threadIdx.x;
    for (int i = tid; i < NBUCKET; i += 256) hist[i] = 0;
    __syncthreads();
    int base = blockIdx.x * 4096;
    unsigned int w[16];
    int bk[16];
    #pragma unroll
    for (int i = 0; i < 16; ++i) {
        int e = base + i * 256 + tid;
        if (e < N_EDGES) {
            int src = edge_index[e];
            int dst = edge_index[N_EDGES + e];
            int r = edge_type[e];
            w[i] = (unsigned int)src | ((unsigned int)r << 16) |
                   ((unsigned int)(dst & 255) << 19);
            bk[i] = dst >> 8;
            atomicAdd(&hist[bk[i]], 1);
        } else {
            bk[i] = -1;
        }
    }
    __syncthreads();
    for (int i = tid; i < NBUCKET; i += 256)
        cur[i] = atomicAdd(&gcnt[i], hist[i]);
    __syncthreads();
    #pragma unroll
    for (int i = 0; i < 16; ++i) {
        if (bk[i] >= 0) {
            int p = atomicAdd(&cur[bk[i]], 1);
            if (p < CAP) slack[(size_t)bk[i] * CAP + p] = w[i];
        }
    }
}

// ---------------------------------------------------------------------------
// bucket_scan: exclusive scan of 196 bucket counts; also set sentinel.
__global__ void bucket_scan(const int* __restrict__ gcnt,
                            int* __restrict__ gbase,
                            int* __restrict__ offsets) {
    __shared__ int sh[256];
    int t = threadIdx.x;
    int v = (t < NBUCKET) ? gcnt[t] : 0;
    sh[t] = v;
    __syncthreads();
    #pragma unroll
    for (int off = 1; off < 256; off <<= 1) {
        int x = (t >= off) ? sh[t - off] : 0;
        __syncthreads();
        sh[t] += x;
        __syncthreads();
    }
    if (t < NBUCKET) gbase[t] = sh[t] - v;
    if (t == 0) offsets[NSEG] = N_EDGES;
}

// ---------------------------------------------------------------------------
// bucket_sort: one block per bucket. LDS counting sort over 2048 local segs
// (dstLow*8+rel). Writes sorted_pack (src|rel<<16), offsets, and invcnt.
__global__ __launch_bounds__(256) void bucket_sort(
        const unsigned int* __restrict__ slack,
        const int* __restrict__ gcnt,
        const int* __restrict__ gbase,
        unsigned int* __restrict__ sorted_pack,
        int* __restrict__ offsets,
        float* __restrict__ invcnt) {
    __shared__ unsigned int ebuf[CAP];   // 24 KB
    __shared__ unsigned int obuf[CAP];   // 24 KB
    __shared__ int hist[2048];           // 8 KB (later reused as cursor)
    __shared__ int excl[2048];           // 8 KB
    __shared__ int sh[256];
    int b = blockIdx.x, t = threadIdx.x;
    int n = gcnt[b]; if (n > CAP) n = CAP;
    int bb = gbase[b];
    for (int i = t; i < n; i += 256) ebuf[i] = slack[(size_t)b * CAP + i];
    for (int i = t; i < 2048; i += 256) hist[i] = 0;
    __syncthreads();
    for (int i = t; i < n; i += 256) {
        unsigned int w = ebuf[i];
        int seg = (int)((w >> 19) << 3) | (int)((w >> 16) & 7u);
        atomicAdd(&hist[seg], 1);
    }
    __syncthreads();
    // blocked exclusive scan over 2048: thread t owns [t*8, t*8+8)
    int c[8];
    int s = 0;
    #pragma unroll
    for (int j = 0; j < 8; ++j) { c[j] = hist[t * 8 + j]; s += c[j]; }
    sh[t] = s;
    __syncthreads();
    #pragma unroll
    for (int off = 1; off < 256; off <<= 1) {
        int x = (t >= off) ? sh[t - off] : 0;
        __syncthreads();
        sh[t] += x;
        __syncthreads();
    }
    int ex = sh[t] - s;
    #pragma unroll
    for (int j = 0; j < 8; ++j) { excl[t * 8 + j] = ex; ex += c[j]; }
    __syncthreads();
    #pragma unroll
    for (int j = 0; j < 8; ++j) hist[t * 8 + j] = excl[t * 8 + j];  // cursor
    __syncthreads();
    for (int i = t; i < n; i += 256) {
        unsigned int w = ebuf[i];
        int seg = (int)((w >> 19) << 3) | (int)((w >> 16) & 7u);
        int p = atomicAdd(&hist[seg], 1);
        obuf[p] = w & 0x7ffffu;          // src | rel<<16
    }
    __syncthreads();
    for (int i = t; i < n; i += 256) sorted_pack[bb + i] = obuf[i];
    int segbase = b * 2048;
    #pragma unroll
    for (int j = 0; j < 8; ++j) {
        int gseg = segbase + t * 8 + j;
        if (gseg < NSEG) {
            offsets[gseg] = bb + excl[t * 8 + j];
            invcnt[gseg] = (c[j] > 0) ? 1.0f / (float)c[j] : 0.f;
        }
    }
}

// ---------------------------------------------------------------------------
// cvt_emb: fp32 -> bf16, 2 elems/thread (packed)
__global__ void cvt_emb_kernel(const float* __restrict__ src,
                               unsigned short* __restrict__ dst) {
    int i = blockIdx.x * blockDim.x + threadIdx.x;
    const int npair = N_NODES * DIM / 2;
    if (i >= npair) return;
    float2 v = ((const float2*)src)[i];
    unsigned int p = (unsigned int)f2b(v.x) | ((unsigned int)f2b(v.y) << 16);
    ((unsigned int*)dst)[i] = p;
}

// ---------------------------------------------------------------------------
// cvt_w2: Wt2[s][n][k] bf16 for both layers; s=0 -> root, s>=1 -> W_{s-1}.
__global__ void cvt_w2_kernel(const float* __restrict__ root0,
                              const float* __restrict__ W0,
                              const float* __restrict__ root1,
                              const float* __restrict__ W1,
                              unsigned short* __restrict__ Wt2a,
                              unsigned short* __restrict__ Wt2b) {
    int s = blockIdx.x;        // 0..8
    int n = blockIdx.y;        // 0..127
    int k = threadIdx.x;       // 0..127
    const float* root = blockIdx.z ? root1 : root0;
    const float* W    = blockIdx.z ? W1 : W0;
    unsigned short* Wt2 = blockIdx.z ? Wt2b : Wt2a;
    float v = (s == 0) ? root[k * 128 + n]
                       : W[((size_t)(s - 1) * 128 + k) * 128 + n];
    Wt2[((size_t)s * 128 + n) * 128 + k] = f2b(v);
}

// ---------------------------------------------------------------------------
// gemm9_bn32: Y[s][n][:] = h[n] @ B_s for s=0..8 (slot-major Y).
// r12 structure but BN=32: grid (782, 4) = 3128 blocks -> fills the 8-block/CU
// residency cap (r12's grid of 1564 was occupancy-starved). A-frags loaded
// once to registers; Bs = 8 KB; each wave computes a 32x16 tile (acc 2x1).
__global__ __launch_bounds__(256) void gemm9_bn32(
        const unsigned short* __restrict__ hb,    // N x 128 bf16
        const unsigned short* __restrict__ Wt2,   // 9 x 128(n) x 128(k) bf16
        unsigned short* __restrict__ Y) {         // 9 x N x 128 bf16
    __shared__ unsigned short Bs[32 * 16 * 8];    // 8 KB swizzled

    int tid = threadIdx.x;
    int wave = tid >> 6, lane = tid & 63;
    int wm = wave & 1, wn = wave >> 1;            // 32-row half / 16-col half
    int quad = lane >> 4, l16 = lane & 15;
    int row0 = blockIdx.x * 64;
    int col0 = blockIdx.y * 32;

    // ---- A fragments: direct global -> registers, once ----
    bf16x8 afr[2][4];
    #pragma unroll
    for (int i = 0; i < 2; ++i) {
        int grow = row0 + wm * 32 + i * 16 + l16;
        if (grow >= N_NODES) grow = N_NODES - 1;
        #pragma unroll
        for (int kk = 0; kk < 4; ++kk)
            afr[i][kk] = *(const bf16x8*)(hb + (size_t)grow * DIM + kk * 32 + quad * 8);
    }

    for (int s = 0; s < 9; ++s) {
        __syncthreads();   // previous slot's Bs reads done
        {
            // stage 32 n-rows x 128 k: thread -> row tid>>3, chunks (tid&7)*2..+1
            int n = tid >> 3, c0 = (tid & 7) * 2;
            const unsigned short* gp = Wt2 + ((size_t)s * 128 + col0 + n) * 128 + c0 * 8;
            #pragma unroll
            for (int q = 0; q < 2; ++q)
                *(bf16x8*)&Bs[lds_off(n, c0 + q)] = *(const bf16x8*)(gp + q * 8);
        }
        __syncthreads();

        f32x4 acc[2];
        #pragma unroll
        for (int i = 0; i < 2; ++i) acc[i] = (f32x4){0.f, 0.f, 0.f, 0.f};

        #pragma unroll
        for (int kk = 0; kk < 4; ++kk) {
            int chunk = kk * 4 + quad;
            bf16x8 bfr = *(const bf16x8*)&Bs[lds_off(wn * 16 + l16, chunk)];
            #pragma unroll
            for (int i = 0; i < 2; ++i)
                acc[i] = __builtin_amdgcn_mfma_f32_16x16x32_bf16(
                    afr[i][kk], bfr, acc[i], 0, 0, 0);
        }

        // epilogue: C/D layout col=lane&15, row=(lane>>4)*4+reg
        unsigned short* Ys = Y + (size_t)s * N_NODES * 128;
        #pragma unroll
        for (int i = 0; i < 2; ++i) {
            int gr0 = row0 + wm * 32 + i * 16 + quad * 4;
            int gc = col0 + wn * 16 + l16;
            #pragma unroll
            for (int r = 0; r < 4; ++r) {
                int grow = gr0 + r;
                if (grow < N_NODES)
                    Ys[(size_t)grow * 128 + gc] = f2b(acc[i][r]);
            }
        }
    }
}

// ---------------------------------------------------------------------------
// aggregate_out: one wave per dst.
// hout[dst,:] = relu(bias + Y[0][dst,:] + sum_e inv[dst,rel_e]*Y[1+rel_e][src_e,:])
__global__ __launch_bounds__(256) void aggregate_out(
        const unsigned short* __restrict__ Y,        // 9 x N x 128 bf16
        const float* __restrict__ bias,              // 128
        const int* __restrict__ offsets,             // NSEG+1 (dst-major)
        const unsigned int* __restrict__ sorted_pack,// N_EDGES: src | rel<<16
        const float* __restrict__ invcnt,            // NSEG
        unsigned short* __restrict__ hout) {         // N x 128 bf16
    int dst = blockIdx.x * 4 + (threadIdx.x >> 6);
    if (dst >= N_NODES) return;
    int lane = threadIdx.x & 63;
    const unsigned int* Yu = (const unsigned int*)Y;

    // root slot (s = 0)
    unsigned int r0 = Yu[(size_t)dst * 64 + lane];
    float a0 = blo(r0), a1 = bhi(r0);

    int beg = offsets[dst * N_REL];
    int end = offsets[dst * N_REL + N_REL];
    for (int base = beg; base < end; base += 64) {
        int np = end - base; if (np > 64) np = 64;
        unsigned int pk = 0; float ivl = 0.f;
        if (lane < np) {
            pk = sorted_pack[base + lane];
            ivl = invcnt[dst * N_REL + (int)(pk >> 16)];
        }
        int j = 0;
        for (; j + 7 < np; j += 8) {
            unsigned int pp[8]; float ii[8];
            #pragma unroll
            for (int q = 0; q < 8; ++q) {
                pp[q] = __shfl((int)pk, j + q, 64);
                ii[q] = __shfl(ivl, j + q, 64);
            }
            unsigned int vv[8];
            #pragma unroll
            for (int q = 0; q < 8; ++q)
                vv[q] = Yu[((size_t)(1 + (pp[q] >> 16)) * N_NODES + (pp[q] & 0xffffu)) * 64 + lane];
            #pragma unroll
            for (int q = 0; q < 8; ++q) {
                a0 = fmaf(blo(vv[q]), ii[q], a0);
                a1 = fmaf(bhi(vv[q]), ii[q], a1);
            }
        }
        for (; j < np; ++j) {
            unsigned int pj = __shfl((int)pk, j, 64);
            float ij = __shfl(ivl, j, 64);
            unsigned int v = Yu[((size_t)(1 + (pj >> 16)) * N_NODES + (pj & 0xffffu)) * 64 + lane];
            a0 = fmaf(blo(v), ij, a0); a1 = fmaf(bhi(v), ij, a1);
        }
    }
    float2 bv = ((const float2*)bias)[lane];
    a0 = fmaxf(a0 + bv.x, 0.f);
    a1 = fmaxf(a1 + bv.y, 0.f);
    unsigned int po = (unsigned int)f2b(a0) | ((unsigned int)f2b(a1) << 16);
    ((unsigned int*)(hout + (size_t)dst * DIM))[lane] = po;
}

// ---------------------------------------------------------------------------
// score: out[t] = sum_d h[head,d]*rel_emb[rel,d]*h[tail,d]  (h in bf16)
__global__ void score_kernel(const unsigned short* __restrict__ hb,
                             const float* __restrict__ rel_emb,
                             const int* __restrict__ head,
                             const int* __restrict__ rel,
                             const int* __restrict__ tail,
                             float* __restrict__ out) {
    int t = blockIdx.x * 4 + (threadIdx.x >> 6);
    if (t >= N_TRIP) return;
    int lane = threadIdx.x & 63;
    unsigned int ph = ((const unsigned int*)(hb + (size_t)head[t] * DIM))[lane];
    unsigned int pt = ((const unsigned int*)(hb + (size_t)tail[t] * DIM))[lane];
    float2 rr = ((const float2*)(rel_emb + (size_t)rel[t] * DIM))[lane];
    float s = blo(ph) * rr.x * blo(pt) + bhi(ph) * rr.y * bhi(pt);
    #pragma unroll
    for (int off = 32; off; off >>= 1) s += __shfl_xor(s, off, 64);
    if (lane == 0) out[t] = s;
}

// ---------------------------------------------------------------------------
extern "C" void kernel_launch(void* const* d_in, const int* in_sizes, int n_in,
                              void* d_out, int out_size, void* d_ws, size_t ws_size,
                              hipStream_t stream) {
    const float* emb     = (const float*)d_in[0];
    const float* W0      = (const float*)d_in[1];
    const float* root0   = (const float*)d_in[2];
    const float* b0      = (const float*)d_in[3];
    const float* W1      = (const float*)d_in[4];
    const float* root1   = (const float*)d_in[5];
    const float* b1      = (const float*)d_in[6];
    const float* rel_emb = (const float*)d_in[7];
    const int* edge_index = (const int*)d_in[8];
    const int* edge_type  = (const int*)d_in[9];
    const int* head_idx   = (const int*)d_in[10];
    const int* rel_idx    = (const int*)d_in[11];
    const int* tail_idx   = (const int*)d_in[12];
    float* out = (float*)d_out;

    // workspace layout (~166 MB, all disjoint):
    char* p = (char*)d_ws;
    size_t y_bytes   = (size_t)9 * N_NODES * DIM * sizeof(unsigned short); // 115.2 MB
    size_t hb_bytes  = (size_t)N_NODES * DIM * sizeof(unsigned short);     // 12.8 MB
    size_t wt2_bytes = (size_t)9 * 128 * 128 * sizeof(unsigned short);     // 294912 B
    unsigned short* Y    = (unsigned short*)p; p += y_bytes;
    unsigned short* embb = (unsigned short*)p; p += hb_bytes;
    unsigned short* h1b  = (unsigned short*)p; p += hb_bytes;
    unsigned short* h2b  = (unsigned short*)p; p += hb_bytes;
    unsigned short* Wt2a = (unsigned short*)p; p += wt2_bytes;
    unsigned short* Wt2b = (unsigned short*)p; p += wt2_bytes;
    int* offsets = (int*)p;           p += (size_t)(NSEG + 1) * sizeof(int);
    float* invcnt = (float*)p;        p += (size_t)NSEG * sizeof(float);
    unsigned int* sorted_pack = (unsigned int*)p; p += (size_t)N_EDGES * sizeof(unsigned int);
    unsigned int* slack = (unsigned int*)p; p += (size_t)NBUCKET * CAP * sizeof(unsigned int);
    int* gcnt  = (int*)p;             p += (size_t)NBUCKET * sizeof(int);
    int* gbase = (int*)p;
    (void)ws_size; (void)in_sizes; (void)n_in; (void)out_size;

    dim3 blk256(256);

    // ---- 2-pass bucket sort of edges by (dst, rel), dst-major ----
    hipMemsetAsync(gcnt, 0, (size_t)NBUCKET * sizeof(int), stream);
    bucket_scatter<<<(N_EDGES + 4095) / 4096, blk256, 0, stream>>>(edge_index, edge_type,
                                                                   gcnt, slack);
    bucket_scan<<<1, 256, 0, stream>>>(gcnt, gbase, offsets);
    bucket_sort<<<NBUCKET, blk256, 0, stream>>>(slack, gcnt, gbase, sorted_pack,
                                                offsets, invcnt);

    // ---- precision conversions ----
    cvt_emb_kernel<<<(N_NODES * DIM / 2 + 255) / 256, blk256, 0, stream>>>(emb, embb);
    cvt_w2_kernel<<<dim3(9, 128, 2), 128, 0, stream>>>(root0, W0, root1, W1, Wt2a, Wt2b);

    dim3 ggrid((N_NODES + 63) / 64, 4);            // 782 x 4 = 3128 blocks
    int agrid = (N_NODES + 3) / 4;                 // 12500

    // ---- layer 0: transform then aggregate ----
    gemm9_bn32<<<ggrid, blk256, 0, stream>>>(embb, Wt2a, Y);
    aggregate_out<<<agrid, blk256, 0, stream>>>(Y, b0, offsets, sorted_pack, invcnt, h1b);

    // ---- layer 1 ----
    gemm9_bn32<<<ggrid, blk256, 0, stream>>>(h1b, Wt2b, Y);
    aggregate_out<<<agrid, blk256, 0, stream>>>(Y, b1, offsets, sorted_pack, invcnt, h2b);

    // ---- score ----
    score_kernel<<<(N_TRIP + 3) / 4, blk256, 0, stream>>>(h2b, rel_emb, head_idx, rel_idx,
                                                          tail_idx, out);
}